// Round 5
// baseline (1240.121 us; speedup 1.0000x reference)
//
#include <hip/hip_runtime.h>
#include <stdint.h>

#define NN 100000
#define NE 1600000
#define NG 1000
#define LDA 112   // padded row stride (floats) for xs/h: 448 B, 64B-aligned rows

typedef float f32x4 __attribute__((ext_vector_type(4)));
typedef short s16x8 __attribute__((ext_vector_type(8)));

__device__ __forceinline__ unsigned short f2bf(float f) {
    unsigned u = __builtin_bit_cast(unsigned, f);
    unsigned r = u + 0x7FFFu + ((u >> 16) & 1u);
    return (unsigned short)(r >> 16);
}
__device__ __forceinline__ float bf2f(unsigned short h) {
    unsigned u = ((unsigned)h) << 16;
    return __builtin_bit_cast(float, u);
}

// ---------------- degree / dinv ----------------
__global__ void k_deg(const int* __restrict__ col, int* __restrict__ cnt) {
    int e = blockIdx.x * 256 + threadIdx.x;
    if (e < NE) atomicAdd(&cnt[col[e]], 1);
}

__global__ void k_dinv(const int* __restrict__ cnt, float* __restrict__ dinv) {
    int n = blockIdx.x * 256 + threadIdx.x;
    if (n < NN) dinv[n] = 1.0f / sqrtf((float)cnt[n] + 2.0f);
}

// ---------------- prefix scans for CSR ----------------
__global__ void k_scan1(const int* __restrict__ cnt, int* __restrict__ csum) {
    __shared__ int s[256];
    int i = blockIdx.x * 256 + threadIdx.x;
    s[threadIdx.x] = (i < NN) ? cnt[i] : 0;
    __syncthreads();
    for (int o = 128; o > 0; o >>= 1) {
        if (threadIdx.x < o) s[threadIdx.x] += s[threadIdx.x + o];
        __syncthreads();
    }
    if (threadIdx.x == 0) csum[blockIdx.x] = s[0];
}

__global__ void k_scan2(const int* __restrict__ csum, int* __restrict__ csum2, int nb) {
    __shared__ int s[512];
    int t = threadIdx.x;
    int v = (t < nb) ? csum[t] : 0;
    s[t] = v; __syncthreads();
    for (int o = 1; o < 512; o <<= 1) {
        int x = (t >= o) ? s[t - o] : 0;
        __syncthreads();
        s[t] += x;
        __syncthreads();
    }
    if (t < nb) csum2[t] = s[t] - v;  // exclusive
}

__global__ void k_scan3(const int* __restrict__ cnt, const int* __restrict__ csum2,
                        int* __restrict__ indptr) {
    __shared__ int s[256];
    int t = threadIdx.x;
    int i = blockIdx.x * 256 + t;
    int v = (i < NN) ? cnt[i] : 0;
    s[t] = v; __syncthreads();
    for (int o = 1; o < 256; o <<= 1) {
        int x = (t >= o) ? s[t - o] : 0;
        __syncthreads();
        s[t] += x;
        __syncthreads();
    }
    if (i < NN) indptr[i] = csum2[blockIdx.x] + s[t] - v;
    if (i == 0) indptr[NN] = NE;
}

// scatter: only esrc (ew eliminated via pre-scaled gather table xs)
__global__ void k_scatter(const int* __restrict__ row, const int* __restrict__ col,
                          const int* __restrict__ indptr,
                          int* __restrict__ fill, int* __restrict__ esrc) {
    int e = blockIdx.x * 256 + threadIdx.x;
    if (e >= NE) return;
    int r = row[e], c = col[e];
    int pos = indptr[c] + atomicAdd(&fill[c], 1);
    esrc[pos] = r;
}

// ----- W split+transpose: Wt_{hi,lo}[112][KCP] bf16, zero-padded -----
__global__ void k_convW(const float* __restrict__ W,
                        unsigned short* __restrict__ Whi,
                        unsigned short* __restrict__ Wlo, int K, int KCP) {
    int idx = blockIdx.x * 256 + threadIdx.x;
    if (idx >= 112 * KCP) return;
    int n = idx / KCP, k = idx - n * KCP;
    float v = (n < 100 && k < K) ? W[k * 100 + n] : 0.f;
    unsigned short hi = f2bf(v);
    float r = v - bf2f(hi);
    Whi[idx] = hi;
    Wlo[idx] = f2bf(r);
}

// ---- split-bf16 MFMA GEMM: xs[M x 112] = dinv[m] * (A[M x K, lda] @ W) ----
__global__ __launch_bounds__(256) void k_gemm3(const float* __restrict__ A,
                                               const unsigned short* __restrict__ Wthi,
                                               const unsigned short* __restrict__ Wtlo,
                                               const float* __restrict__ dinv,
                                               float* __restrict__ out,
                                               int M, int K, int KCP, int lda) {
    __shared__ float As[64 * 68];
    __shared__ unsigned short Hs[112 * 72];
    __shared__ unsigned short Ls[112 * 72];
    int t = threadIdx.x;
    int lane = t & 63;
    int wv = t >> 6;
    int l15 = lane & 15, quad = lane >> 4;
    int rowbase = blockIdx.x * 64;

    f32x4 acc[7];
#pragma unroll
    for (int i = 0; i < 7; i++)
#pragma unroll
        for (int r = 0; r < 4; r++) acc[i][r] = 0.f;

    for (int k0 = 0; k0 < KCP; k0 += 64) {
        __syncthreads();
#pragma unroll
        for (int j = 0; j < 4; j++) {
            int e = t + j * 256;
            int r = e >> 4;
            int c4 = (e & 15) * 4;
            int gr = rowbase + r, gk = k0 + c4;
            float4 v = make_float4(0.f, 0.f, 0.f, 0.f);
            if (gr < M && gk < K) v = *(const float4*)(A + (size_t)gr * lda + gk);
            *(float4*)(&As[r * 68 + c4]) = v;
        }
#pragma unroll
        for (int j = 0; j < 7; j++) {
            int e = t + j * 256;
            int n = e >> 4;
            int c = (e & 15) * 4;
            size_t g = (size_t)n * KCP + k0 + c;
            *(uint2*)(&Hs[n * 72 + c]) = *(const uint2*)(Wthi + g);
            *(uint2*)(&Ls[n * 72 + c]) = *(const uint2*)(Wtlo + g);
        }
        __syncthreads();
#pragma unroll
        for (int ks = 0; ks < 2; ks++) {
            int arow = wv * 16 + l15;
            const float* ap = &As[arow * 68 + ks * 32 + quad * 8];
            float4 a0 = *(const float4*)ap;
            float4 a1 = *(const float4*)(ap + 4);
            float af[8] = {a0.x, a0.y, a0.z, a0.w, a1.x, a1.y, a1.z, a1.w};
            s16x8 ahi, alo;
#pragma unroll
            for (int j = 0; j < 8; j++) {
                unsigned short h = f2bf(af[j]);
                ahi[j] = (short)h;
                alo[j] = (short)f2bf(af[j] - bf2f(h));
            }
            int koff = ks * 32 + quad * 8;
#pragma unroll
            for (int tt = 0; tt < 7; tt++) {
                int nrow = tt * 16 + l15;
                s16x8 bhi = *(const s16x8*)(&Hs[nrow * 72 + koff]);
                s16x8 blo = *(const s16x8*)(&Ls[nrow * 72 + koff]);
                acc[tt] = __builtin_amdgcn_mfma_f32_16x16x32_bf16(ahi, bhi, acc[tt], 0, 0, 0);
                acc[tt] = __builtin_amdgcn_mfma_f32_16x16x32_bf16(ahi, blo, acc[tt], 0, 0, 0);
                acc[tt] = __builtin_amdgcn_mfma_f32_16x16x32_bf16(alo, bhi, acc[tt], 0, 0, 0);
            }
        }
    }

    // store all 112 cols, scaled by dinv[row] (pad cols are exact zeros)
    int gr0 = rowbase + wv * 16 + quad * 4;
    float dv[4];
#pragma unroll
    for (int reg = 0; reg < 4; reg++) dv[reg] = (gr0 + reg < M) ? dinv[gr0 + reg] : 0.f;
#pragma unroll
    for (int tt = 0; tt < 7; tt++) {
        int n = tt * 16 + l15;
#pragma unroll
        for (int reg = 0; reg < 4; reg++) {
            int gr = gr0 + reg;
            if (gr < M) out[(size_t)gr * LDA + n] = dv[reg] * acc[tt][reg];
        }
    }
}

// ---- aggregation: h[n] = relu(dinv[n]*(sum_e xs[src] + 2*xs[n]) + b) ----
// one wave per node; cooperative esrc load + readlane broadcast; up to 16
// gathers in flight. lanes 0..49 own a float2; 50..63 clamp to col 0.
__global__ __launch_bounds__(256) void k_agg(const float* __restrict__ xs,
                                             const int* __restrict__ indptr,
                                             const int* __restrict__ esrc,
                                             const float* __restrict__ dinv,
                                             const float* __restrict__ bias,
                                             float* __restrict__ hout) {
    int wave = threadIdx.x >> 6;
    int lane = threadIdx.x & 63;
    int n = blockIdx.x * 4 + wave;
    if (n >= NN) return;
    int beg = indptr[n], end = indptr[n + 1];
    int col = (lane < 50) ? lane * 2 : 0;
    float ax = 0.f, ay = 0.f;
    for (int c = beg; c < end; c += 64) {
        int m = min(64, end - c);
        int se = 0;
        if (lane < m) se = esrc[c + lane];
        int j = 0;
        for (; j + 16 <= m; j += 16) {
            float2 v[16];
#pragma unroll
            for (int u = 0; u < 16; u++) {
                int s = __builtin_amdgcn_readlane(se, j + u);
                v[u] = *(const float2*)(xs + (size_t)s * LDA + col);
            }
#pragma unroll
            for (int u = 0; u < 16; u++) { ax += v[u].x; ay += v[u].y; }
        }
        for (; j + 8 <= m; j += 8) {
            float2 v[8];
#pragma unroll
            for (int u = 0; u < 8; u++) {
                int s = __builtin_amdgcn_readlane(se, j + u);
                v[u] = *(const float2*)(xs + (size_t)s * LDA + col);
            }
#pragma unroll
            for (int u = 0; u < 8; u++) { ax += v[u].x; ay += v[u].y; }
        }
        for (; j + 4 <= m; j += 4) {
            float2 v[4];
#pragma unroll
            for (int u = 0; u < 4; u++) {
                int s = __builtin_amdgcn_readlane(se, j + u);
                v[u] = *(const float2*)(xs + (size_t)s * LDA + col);
            }
#pragma unroll
            for (int u = 0; u < 4; u++) { ax += v[u].x; ay += v[u].y; }
        }
        for (; j < m; j++) {
            int s = __builtin_amdgcn_readlane(se, j);
            float2 v = *(const float2*)(xs + (size_t)s * LDA + col);
            ax += v.x; ay += v.y;
        }
    }
    if (lane < 50) {
        float di = dinv[n];
        float2 xv = *(const float2*)(xs + (size_t)n * LDA + col);
        float2 bv = *(const float2*)(bias + lane * 2);
        float2 r;
        r.x = fmaxf(di * (ax + 2.f * xv.x) + bv.x, 0.f);
        r.y = fmaxf(di * (ay + 2.f * xv.y) + bv.y, 0.f);
        *(float2*)(hout + (size_t)n * LDA + col) = r;
    }
}

// ---------------- pooling ----------------
__global__ void k_gcount(const int* __restrict__ batch, int* __restrict__ gcnt) {
    int n = blockIdx.x * 256 + threadIdx.x;
    if (n < NN) atomicAdd(&gcnt[batch[n]], 1);
}

__global__ void k_gscan(const int* __restrict__ gcnt, int* __restrict__ gstart) {
    __shared__ int s[1024];
    int t = threadIdx.x;
    int v = (t < NG) ? gcnt[t] : 0;
    s[t] = v; __syncthreads();
    for (int o = 1; o < 1024; o <<= 1) {
        int x = (t >= o) ? s[t - o] : 0;
        __syncthreads();
        s[t] += x;
        __syncthreads();
    }
    if (t < NG) gstart[t] = s[t] - v;
}

__global__ void k_pool(const float* __restrict__ h, const int* __restrict__ gcnt,
                       const int* __restrict__ gstart, float* __restrict__ pooled) {
    int g = blockIdx.x, t = threadIdx.x;
    if (t >= 100) return;
    int cnt = gcnt[g], st = gstart[g];
    float s = 0.f;
    for (int i = 0; i < cnt; i++) s += h[(size_t)(st + i) * LDA + t];
    pooled[g * 100 + t] = s / (float)(cnt > 0 ? cnt : 1);
}

// ---------------- MLP head (fused 3 layers, one block per graph) ----------------
__global__ void k_mlp(const float* __restrict__ pooled,
                      const float* __restrict__ Wl1, const float* __restrict__ bl1,
                      const float* __restrict__ Wl2, const float* __restrict__ bl2,
                      const float* __restrict__ Wl3, const float* __restrict__ bl3,
                      float* __restrict__ out) {
    __shared__ float p[100], q[100];
    int g = blockIdx.x, t = threadIdx.x;
    if (t < 100) p[t] = pooled[g * 100 + t];
    __syncthreads();
    float s1 = 0.f;
    if (t < 100) {
        s1 = bl1[t];
        for (int k = 0; k < 100; k++) s1 += p[k] * Wl1[k * 100 + t];
        s1 = fmaxf(s1, 0.f);
    }
    __syncthreads();
    if (t < 100) q[t] = s1;
    __syncthreads();
    float s2 = 0.f;
    if (t < 100) {
        s2 = bl2[t];
        for (int k = 0; k < 100; k++) s2 += q[k] * Wl2[k * 100 + t];
        s2 = fmaxf(s2, 0.f);
    }
    __syncthreads();
    if (t < 100) p[t] = s2;
    __syncthreads();
    if (t < 29) {
        float s3 = bl3[t];
        for (int k = 0; k < 100; k++) s3 += p[k] * Wl3[k * 29 + t];
        out[g * 29 + t] = s3;
    }
}

// ---------------- launch ----------------
extern "C" void kernel_launch(void* const* d_in, const int* in_sizes, int n_in,
                              void* d_out, int out_size, void* d_ws, size_t ws_size,
                              hipStream_t stream) {
    const float* x     = (const float*)d_in[0];
    const int*   ei    = (const int*)d_in[1];
    const int*   batch = (const int*)d_in[2];
    const float* W1 = (const float*)d_in[3];  const float* b1 = (const float*)d_in[4];
    const float* W2 = (const float*)d_in[5];  const float* b2 = (const float*)d_in[6];
    const float* W3 = (const float*)d_in[7];  const float* b3 = (const float*)d_in[8];
    const float* W4 = (const float*)d_in[9];  const float* b4 = (const float*)d_in[10];
    const float* W5 = (const float*)d_in[11]; const float* b5 = (const float*)d_in[12];
    const float* Wl1 = (const float*)d_in[13]; const float* bl1 = (const float*)d_in[14];
    const float* Wl2 = (const float*)d_in[15]; const float* bl2 = (const float*)d_in[16];
    const float* Wl3 = (const float*)d_in[17]; const float* bl3 = (const float*)d_in[18];
    float* out = (float*)d_out;

    const int* row = ei;
    const int* col = ei + NE;

    uintptr_t base = (uintptr_t)d_ws;
    auto alloc = [&](size_t bytes) -> void* {
        void* p = (void*)base;
        base += (bytes + 255) & ~(size_t)255;
        return p;
    };
    int*   degcnt = (int*)alloc(NN * 4);
    float* dinv   = (float*)alloc(NN * 4);
    int*   indptr = (int*)alloc((NN + 1) * 4);
    int*   fill   = (int*)alloc(NN * 4);
    int*   csum   = (int*)alloc(512 * 4);
    int*   csum2  = (int*)alloc(512 * 4);
    int*   gcnt   = (int*)alloc(1024 * 4);
    int*   gstart = (int*)alloc(1024 * 4);
    int*   esrc   = (int*)alloc((size_t)NE * 4);
    float* xs     = (float*)alloc((size_t)NN * LDA * 4);
    float* h      = (float*)alloc((size_t)NN * LDA * 4);
    float* pooled = (float*)alloc((size_t)NG * 100 * 4);
    unsigned short* w1hi = (unsigned short*)alloc((size_t)112 * 384 * 2);
    unsigned short* w1lo = (unsigned short*)alloc((size_t)112 * 384 * 2);
    unsigned short* w2hi = (unsigned short*)alloc((size_t)112 * 128 * 2);
    unsigned short* w2lo = (unsigned short*)alloc((size_t)112 * 128 * 2);
    unsigned short* w3hi = (unsigned short*)alloc((size_t)112 * 128 * 2);
    unsigned short* w3lo = (unsigned short*)alloc((size_t)112 * 128 * 2);
    unsigned short* w4hi = (unsigned short*)alloc((size_t)112 * 128 * 2);
    unsigned short* w4lo = (unsigned short*)alloc((size_t)112 * 128 * 2);
    unsigned short* w5hi = (unsigned short*)alloc((size_t)112 * 128 * 2);
    unsigned short* w5lo = (unsigned short*)alloc((size_t)112 * 128 * 2);

    hipMemsetAsync(degcnt, 0, NN * 4, stream);
    hipMemsetAsync(fill, 0, NN * 4, stream);
    hipMemsetAsync(gcnt, 0, 1024 * 4, stream);

    const int NB = (NN + 255) / 256;  // 391
    k_deg<<<(NE + 255) / 256, 256, 0, stream>>>(col, degcnt);
    k_dinv<<<NB, 256, 0, stream>>>(degcnt, dinv);
    k_scan1<<<NB, 256, 0, stream>>>(degcnt, csum);
    k_scan2<<<1, 512, 0, stream>>>(csum, csum2, NB);
    k_scan3<<<NB, 256, 0, stream>>>(degcnt, csum2, indptr);
    k_scatter<<<(NE + 255) / 256, 256, 0, stream>>>(row, col, indptr, fill, esrc);

    k_convW<<<(112 * 384 + 255) / 256, 256, 0, stream>>>(W1, w1hi, w1lo, 336, 384);
    k_convW<<<(112 * 128 + 255) / 256, 256, 0, stream>>>(W2, w2hi, w2lo, 100, 128);
    k_convW<<<(112 * 128 + 255) / 256, 256, 0, stream>>>(W3, w3hi, w3lo, 100, 128);
    k_convW<<<(112 * 128 + 255) / 256, 256, 0, stream>>>(W4, w4hi, w4lo, 100, 128);
    k_convW<<<(112 * 128 + 255) / 256, 256, 0, stream>>>(W5, w5hi, w5lo, 100, 128);

    const int GEMM_GRID = (NN + 63) / 64;  // 1563
    const int AGG_GRID = (NN + 3) / 4;     // 25000

    k_gemm3<<<GEMM_GRID, 256, 0, stream>>>(x, w1hi, w1lo, dinv, xs, NN, 336, 384, 336);
    k_agg<<<AGG_GRID, 256, 0, stream>>>(xs, indptr, esrc, dinv, b1, h);
    k_gemm3<<<GEMM_GRID, 256, 0, stream>>>(h, w2hi, w2lo, dinv, xs, NN, 100, 128, LDA);
    k_agg<<<AGG_GRID, 256, 0, stream>>>(xs, indptr, esrc, dinv, b2, h);
    k_gemm3<<<GEMM_GRID, 256, 0, stream>>>(h, w3hi, w3lo, dinv, xs, NN, 100, 128, LDA);
    k_agg<<<AGG_GRID, 256, 0, stream>>>(xs, indptr, esrc, dinv, b3, h);
    k_gemm3<<<GEMM_GRID, 256, 0, stream>>>(h, w4hi, w4lo, dinv, xs, NN, 100, 128, LDA);
    k_agg<<<AGG_GRID, 256, 0, stream>>>(xs, indptr, esrc, dinv, b4, h);
    k_gemm3<<<GEMM_GRID, 256, 0, stream>>>(h, w5hi, w5lo, dinv, xs, NN, 100, 128, LDA);
    k_agg<<<AGG_GRID, 256, 0, stream>>>(xs, indptr, esrc, dinv, b5, h);

    k_gcount<<<NB, 256, 0, stream>>>(batch, gcnt);
    k_gscan<<<1, 1024, 0, stream>>>(gcnt, gstart);
    k_pool<<<NG, 128, 0, stream>>>(h, gcnt, gstart, pooled);
    k_mlp<<<NG, 128, 0, stream>>>(pooled, Wl1, bl1, Wl2, bl2, Wl3, bl3, out);
}